// Round 9
// baseline (280.794 us; speedup 1.0000x reference)
//
#include <hip/hip_runtime.h>
#include <stdint.h>
#include <stddef.h>

// EfficientAttention: B=4, L=4096, D=1024, H=16, hd=64. Inputs fp32.
// R10: FP16 single-term (verified). attn_mix: out = (smQ·sK)·V, M 16x16.
// R11 (verified): 256x256 tile, 512thr/8 waves (2Mx4N), 128KB LDS, merged
//   single pass M=16384: 120us, MfmaUtil 36%.
// R13 (4-phase, 2 barriers/phase, vmcnt(0)/tile): only 114.5us, MfmaUtil 38%.
//   Lesson: barrier-lockstep serializes LDS-read and MFMA intervals; and
//   2-deep dbuf caps load lead-time < HBM latency, so the vmcnt(0) drain
//   stalls. T4 (counted vmcnt) needs >=3-deep buffering.
// R14: BK=32, FOUR buffers (same 128KB), depth-3 prefetch (stage t+3 during
//   t, ~2000cyc lead), counted vmcnt(8) at tile entry (t+1,t+2 loads stay in
//   flight ACROSS the barrier -- m218's isolated +38-73% lever), ONE raw
//   s_barrier per tile, no __syncthreads in loop. Race audit: RAW = own
//   vmcnt(8) pre-barrier + barrier; WAR = re-staged buffer's readers done
//   under prior tile's lgkmcnt(0) before prior barrier; uniform branches.
//   Swizzle = R4's verified-zero-conflict BK=32 pattern (chunk ^ (row>>1)&3,
//   both sides). K-order unchanged -> absmax must stay exactly 0.0078125.
// NOTE R5: over-tight bounds force spills (FETCH explodes). Canary ~74MB.
// R4 lesson: attn_mix ~110us w/o counters; once gemm < 110 it tops the PMC.
#define TOKENS 16384
#define CHUNK  8192
#define DMODEL 1024

typedef short   short8 __attribute__((ext_vector_type(8)));
typedef _Float16 half8 __attribute__((ext_vector_type(8)));
typedef float   f32x4  __attribute__((ext_vector_type(4)));
typedef unsigned short ushort_t;
typedef unsigned short us4 __attribute__((ext_vector_type(4)));

__device__ inline ushort_t f2h(float f) {
  union { _Float16 h; ushort_t u; } x; x.h = (_Float16)f; return x.u;
}
__device__ inline float h2f(ushort_t u) {
  union { _Float16 h; ushort_t u; } x; x.u = u; return (float)x.h;
}

// ---- FP16 MFMA wrapper: dual-signature hedge (short8 vs v8f16 builtin arg) ----
template <typename V>
__device__ auto mfma16h_(V a, V b, f32x4 c, int)
    -> decltype(__builtin_amdgcn_mfma_f32_16x16x32_f16(a, b, c, 0, 0, 0)) {
  return __builtin_amdgcn_mfma_f32_16x16x32_f16(a, b, c, 0, 0, 0);
}
template <typename V>
__device__ f32x4 mfma16h_(V a, V b, f32x4 c, long) {
  return __builtin_amdgcn_mfma_f32_16x16x32_f16(
      __builtin_bit_cast(half8, a), __builtin_bit_cast(half8, b), c, 0, 0, 0);
}
__device__ inline f32x4 MFMA16H(short8 a, short8 b, f32x4 c) {
  return mfma16h_(a, b, c, 0);
}

__device__ inline void gload_lds16(const void* g, void* l) {
  __builtin_amdgcn_global_load_lds(
      (const __attribute__((address_space(1))) unsigned int*)g,
      (__attribute__((address_space(3))) unsigned int*)l, 16, 0, 0);
}

// intra-wave LDS fence (attn_mix): cross-lane ds_write -> ds_read within ONE
// wave needs only lgkmcnt(0), no s_barrier. sched_barrier stops hoisting
// past the asm (rule #18).
__device__ inline void wave_lds_fence() {
  asm volatile("s_waitcnt lgkmcnt(0)" ::: "memory");
  __builtin_amdgcn_sched_barrier(0);
}

// ---- W -> fp16, all three weights in one launch ----
__global__ __launch_bounds__(256) void conv_w(
    const float* __restrict__ Wq, const float* __restrict__ Wk,
    const float* __restrict__ Wv, ushort_t* __restrict__ Wh, int n4)
{
  int i = blockIdx.x * 256 + threadIdx.x;
  if (i >= n4) return;
  const float* src = (blockIdx.y == 0) ? Wq : ((blockIdx.y == 1) ? Wk : Wv);
  f32x4 x = ((const f32x4*)src)[i];
  us4 h;
  #pragma unroll
  for (int j = 0; j < 4; ++j) h[j] = f2h(x[j]);
  ((us4*)(Wh + (size_t)blockIdx.y * DMODEL * DMODEL))[i] = h;
}

// ---- X -> fp16 ----
__global__ __launch_bounds__(256) void conv_x(
    const float* __restrict__ src, ushort_t* __restrict__ dst, int n4)
{
  int i = blockIdx.x * 256 + threadIdx.x;
  if (i >= n4) return;
  f32x4 x = ((const f32x4*)src)[i];
  us4 h;
  #pragma unroll
  for (int j = 0; j < 4; ++j) h[j] = f2h(x[j]);
  ((us4*)dst)[i] = h;
}

// ------- GEMM: Y[z] = X @ W[z]^T, fp16, 256x256 tile, BK=32, 4-buf -------
// 8 waves 2Mx4N; per-wave 128x64 out = 8x4 f32x4 acc.
// LDS [4][256 rows][4 chunks of 16B] per matrix (4x16KB x2 = 128KB).
// Swizzle (R4-verified zero-conflict): phys chunk = logical ^ ((row>>1)&3);
// both sides: pre-swizzled global source + same XOR on fragment read.
// Per-tile schedule: {vmcnt(8); s_barrier; stage(t+3) [4 gload_lds];
//   ds_read 12 b128; lgkmcnt(0); setprio(1); 32 MFMA; setprio(0)}.
// Loads for t+1/t+2 remain in flight across the barrier (T4 counted-vmcnt).
__global__ __launch_bounds__(512, 2) void gemm_h(
    const ushort_t* __restrict__ Xh, const ushort_t* __restrict__ Wh,
    ushort_t* __restrict__ Y, int tokens)
{
  __shared__ ushort_t As[4][256 * 32];  // 16 KB per buffer
  __shared__ ushort_t Bs[4][256 * 32];

  const int tid  = threadIdx.x;
  const int lane = tid & 63;
  const int wid  = tid >> 6;     // 0..7
  const int quad = lane >> 4;
  const int l15  = lane & 15;
  const int wm   = wid >> 2;     // 0..1  (M split)
  const int wn   = wid & 3;      // 0..3  (N split)

  const int m0 = blockIdx.x * 256;
  const int n0 = blockIdx.y * 256;
  const int z  = blockIdx.z;

  const ushort_t* Ag = Xh + (size_t)m0 * DMODEL;
  const ushort_t* Bg = Wh + (size_t)z * DMODEL * DMODEL + (size_t)n0 * DMODEL;
  ushort_t* Yp = Y + (size_t)z * tokens * DMODEL;

  f32x4 acc[8][4] = {};

  // stage K-tile t into buffer t&3: per thread 2 chunks x (A,B) = 4 gloads.
  // chunk c = i*512 + tid: row = c>>2, logical chunk = c&3; LDS dest linear
  // (uniform base + lane*16 by HW); global k-offset pre-swizzled (rule #21).
  auto stage = [&](int t) {
    const int b = t & 3;
    const int kbase = t * 32;
    #pragma unroll
    for (int i = 0; i < 2; ++i) {
      const int c    = i * 512 + tid;
      const int row  = c >> 2;
      const int koff = (((c & 3) ^ ((row >> 1) & 3)) << 3);
      const size_t g = (size_t)row * DMODEL + kbase + koff;
      const int ldso = (i * 512 + wid * 64) * 16;
      gload_lds16(Ag + g, (char*)As[b] + ldso);
      gload_lds16(Bg + g, (char*)Bs[b] + ldso);
    }
  };

  stage(0);
  stage(1);
  stage(2);

  for (int t = 0; t < DMODEL / 32; ++t) {
    // counted wait: newer loads (t+1,t+2) = 8 stay in flight; taper at tail.
    if (t < 30)       asm volatile("s_waitcnt vmcnt(8)" ::: "memory");
    else if (t == 30) asm volatile("s_waitcnt vmcnt(4)" ::: "memory");
    else              asm volatile("s_waitcnt vmcnt(0)" ::: "memory");
    __builtin_amdgcn_sched_barrier(0);
    __builtin_amdgcn_s_barrier();          // raw: no waitcnt drain attached
    __builtin_amdgcn_sched_barrier(0);

    if (t + 3 < DMODEL / 32) stage(t + 3); // uniform cond, no divergence

    const int b = t & 3;
    const short8* Av = (const short8*)As[b];  // index = row*4 + phys chunk
    const short8* Bv = (const short8*)Bs[b];

    short8 ah[8], bh[4];
    #pragma unroll
    for (int f = 0; f < 8; ++f) {
      const int r = wm * 128 + f * 16 + l15;
      ah[f] = Av[r * 4 + (quad ^ ((r >> 1) & 3))];
    }
    #pragma unroll
    for (int j = 0; j < 4; ++j) {
      const int r = wn * 64 + j * 16 + l15;
      bh[j] = Bv[r * 4 + (quad ^ ((r >> 1) & 3))];
    }

    asm volatile("s_waitcnt lgkmcnt(0)" ::: "memory");
    __builtin_amdgcn_sched_barrier(0);     // rule #18
    __builtin_amdgcn_s_setprio(1);
    #pragma unroll
    for (int f = 0; f < 8; ++f) {
      #pragma unroll
      for (int j = 0; j < 4; ++j)
        acc[f][j] = MFMA16H(ah[f], bh[j], acc[f][j]);
    }
    __builtin_amdgcn_s_setprio(0);
  }

  // C/D layout: col = lane&15, row = quad*4 + reg (verified pattern)
  #pragma unroll
  for (int i = 0; i < 8; ++i) {
    #pragma unroll
    for (int j = 0; j < 4; ++j) {
      #pragma unroll
      for (int r = 0; r < 4; ++r) {
        int row = m0 + wm * 128 + i * 16 + quad * 4 + r;
        int col = n0 + wn * 64 + j * 16 + l15;
        Yp[(size_t)row * DMODEL + col] = f2h(acc[i][j][r]);
      }
    }
  }
}

// ---------------- Phase 2: per-token mixing (1 wave/token) ----------------
// out = (smQ . sK) . V ; M = smQ.sK is 16x16, via 2 fp16 MFMAs with Q,K
// loaded straight into fragment layout (no LDS for Q/K):
//   lane l: row = l&15, k-slices quad*8 (kh0) and 32+quad*8 (kh1).
// Softmax in fragment layout, no max-subtract (N(0,1) data, fp32-safe):
//   K (over h'): per-slot lane-sums xor{1,2,4,8}; norm folded into A side.
//   Q (over d):  in-lane 16-sum + xor{16,32}.
// LDS: only V (broadcast b128 in out-phase) + M. 14.3 KB/block.
__global__ __launch_bounds__(256) void attn_mix(
    const ushort_t* __restrict__ QKV, float* __restrict__ Out, int tokens)
{
  __shared__ __align__(16) ushort_t V_s[4][16 * 72];  // stride 72 shorts
  __shared__ __align__(16) float    M_s[4][16 * 20];  // stride 20 floats

  const int tid  = threadIdx.x;
  const int lane = tid & 63;
  const int wv   = tid >> 6;
  const int tok  = blockIdx.x * 4 + wv;

  const int l15  = lane & 15;
  const int quad = lane >> 4;
  const int hrow = lane >> 3;        // V/out row pair {hrow, hrow+8}
  const int dcol = (lane & 7) * 8;   // V/out e-slice start

  ushort_t* Vl = V_s[wv];
  float*    Ml = M_s[wv];

  const size_t base = (size_t)tok * DMODEL;
  const size_t zstr = (size_t)tokens * DMODEL;
  const short8* Q8 = (const short8*)(QKV + base);
  const short8* K8 = (const short8*)(QKV + zstr + base);
  const short8* V8 = (const short8*)(QKV + 2 * zstr + base);

  // ---- V coalesced -> LDS (fp16 bits, read back broadcast in out-phase) ----
  short8 vra = V8[lane], vrb = V8[64 + lane];
  *(short8*)(Vl + hrow * 72 + dcol)       = vra;
  *(short8*)(Vl + (hrow + 8) * 72 + dcol) = vrb;

  // ---- Q,K in fragment layout: 16 full 64B lines per instruction ----
  const int fidx = l15 * 8 + quad;
  short8 qf0 = Q8[fidx], qf1 = Q8[fidx + 4];
  short8 kf0 = K8[fidx], kf1 = K8[fidx + 4];

  float eq0[8], eq1[8], ek0[8], ek1[8];
  #pragma unroll
  for (int j = 0; j < 8; ++j) {
    eq0[j] = __expf(h2f((ushort_t)qf0[j]));
    eq1[j] = __expf(h2f((ushort_t)qf1[j]));
    ek0[j] = __expf(h2f((ushort_t)kf0[j]));
    ek1[j] = __expf(h2f((ushort_t)kf1[j]));
  }

  // ---- K sums S[d] over h' (reduce over l15 within quad group) ----
  float s0[8], s1[8];
  #pragma unroll
  for (int j = 0; j < 8; ++j) { s0[j] = ek0[j]; s1[j] = ek1[j]; }
  #pragma unroll
  for (int j = 0; j < 8; ++j) {
    s0[j] += __shfl_xor(s0[j], 1);
    s0[j] += __shfl_xor(s0[j], 2);
    s0[j] += __shfl_xor(s0[j], 4);
    s0[j] += __shfl_xor(s0[j], 8);
    s1[j] += __shfl_xor(s1[j], 1);
    s1[j] += __shfl_xor(s1[j], 2);
    s1[j] += __shfl_xor(s1[j], 4);
    s1[j] += __shfl_xor(s1[j], 8);
  }

  // ---- Q sum over all 64 d: in-lane 16 + quads xor{16,32} ----
  float sq = 0.f;
  #pragma unroll
  for (int j = 0; j < 8; ++j) sq += eq0[j] + eq1[j];
  sq += __shfl_xor(sq, 16);
  sq += __shfl_xor(sq, 32);
  const float invSq = __builtin_amdgcn_rcpf(sq);

  // ---- A = eQ * invSq * invS[d] (fp16), B = eK (fp16) ----
  short8 a0v, a1v, b0v, b1v;
  #pragma unroll
  for (int j = 0; j < 8; ++j) {
    a0v[j] = (short)f2h(eq0[j] * (invSq * __builtin_amdgcn_rcpf(s0[j])));
    a1v[j] = (short)f2h(eq1[j] * (invSq * __builtin_amdgcn_rcpf(s1[j])));
    b0v[j] = (short)f2h(ek0[j]);
    b1v[j] = (short)f2h(ek1[j]);
  }

  // ---- M = A . B^T via 2 fp16 MFMAs ----
  f32x4 acc = {};
  acc = MFMA16H(a0v, b0v, acc);
  acc = MFMA16H(a1v, b1v, acc);

  // C/D: M[row=quad*4+r][col=l15]
  #pragma unroll
  for (int r = 0; r < 4; ++r) Ml[(quad * 4 + r) * 20 + l15] = acc[r];

  wave_lds_fence();

  // ---- out[h][e] = sum_h' M[h][h'] * V[h'][e], h in {hrow,hrow+8} ----
  f32x4 m0[4], m1[4];
  #pragma unroll
  for (int j = 0; j < 4; ++j) {
    m0[j] = *(const f32x4*)(Ml + hrow * 20 + j * 4);
    m1[j] = *(const f32x4*)(Ml + (hrow + 8) * 20 + j * 4);
  }
  float o0[8] = {0.f, 0.f, 0.f, 0.f, 0.f, 0.f, 0.f, 0.f};
  float o1[8] = {0.f, 0.f, 0.f, 0.f, 0.f, 0.f, 0.f, 0.f};
  #pragma unroll
  for (int hp = 0; hp < 16; ++hp) {
    short8 vv = *(const short8*)(Vl + hp * 72 + dcol);  // 8-way broadcast read
    const float w0 = m0[hp >> 2][hp & 3];
    const float w1 = m1[hp >> 2][hp & 3];
    #pragma unroll
    for (int j = 0; j < 8; ++j) {
      float vf = h2f((ushort_t)vv[j]);
      o0[j] += w0 * vf;
      o1[j] += w1 * vf;
    }
  }

  float* O0 = Out + base + hrow * 64 + dcol;
  float* O1 = Out + base + (hrow + 8) * 64 + dcol;
  f32x4 w;
  w[0] = o0[0]; w[1] = o0[1]; w[2] = o0[2]; w[3] = o0[3]; *(f32x4*)(O0)     = w;
  w[0] = o0[4]; w[1] = o0[5]; w[2] = o0[6]; w[3] = o0[7]; *(f32x4*)(O0 + 4) = w;
  w[0] = o1[0]; w[1] = o1[1]; w[2] = o1[2]; w[3] = o1[3]; *(f32x4*)(O1)     = w;
  w[0] = o1[4]; w[1] = o1[5]; w[2] = o1[6]; w[3] = o1[7]; *(f32x4*)(O1 + 4) = w;
}

extern "C" void kernel_launch(void* const* d_in, const int* in_sizes, int n_in,
                              void* d_out, int out_size, void* d_ws, size_t ws_size,
                              hipStream_t stream) {
  const float* X  = (const float*)d_in[0];
  const float* Wq = (const float*)d_in[1];
  const float* Wk = (const float*)d_in[2];
  const float* Wv = (const float*)d_in[3];
  float* Out = (float*)d_out;

  const size_t WSZ = (size_t)DMODEL * DMODEL;

  // Adaptive chunking: single pass (M=16384, 768 gemm blocks = 3 full
  // rounds at 1 block/CU) if ws fits Wh 6MB + Xh 32MB + Y 96MB = 140MB.
  const size_t need1 = (3 * WSZ + (size_t)TOKENS * DMODEL * 4) * sizeof(ushort_t);
  const int    nck  = (ws_size >= need1) ? 1 : 2;
  const size_t ctok = (nck == 1) ? (size_t)TOKENS : (size_t)CHUNK;

  ushort_t* Wh = (ushort_t*)d_ws;
  ushort_t* Xh = Wh + 3 * WSZ;
  ushort_t* Yw = Xh + ctok * DMODEL;

  const int wn4 = (int)(WSZ / 4);
  dim3 gw((wn4 + 255) / 256, 3);
  conv_w<<<gw, 256, 0, stream>>>(Wq, Wk, Wv, Wh, wn4);

  const int xn4 = (int)(ctok * DMODEL / 4);
  dim3 gg((unsigned)(ctok / 256), DMODEL / 256, 3);
  for (int c = 0; c < nck; ++c) {
    conv_x<<<(xn4 + 255) / 256, 256, 0, stream>>>(X + c * ctok * DMODEL, Xh, xn4);
    gemm_h<<<gg, 512, 0, stream>>>(Xh, Wh, Yw, (int)ctok);
    attn_mix<<<(unsigned)(ctok / 4), 256, 0, stream>>>(Yw, Out + c * ctok * DMODEL, (int)ctok);
  }
}

// Round 10
// 270.410 us; speedup vs baseline: 1.0384x; 1.0384x over previous
//
#include <hip/hip_runtime.h>
#include <stdint.h>
#include <stddef.h>

// EfficientAttention: B=4, L=4096, D=1024, H=16, hd=64. Inputs fp32.
// R10: FP16 single-term (verified). attn_mix: out = (smQ·sK)·V, M 16x16.
// R13 (BEST gemm, verified 114.5us, MfmaUtil 38%): 256x256, BK=64, 4-phase
//   M-quadrant interleave, 2 barriers/phase, vmcnt(0)+syncthreads per tile.
// R14 (REGRESSED 140us, reverted): BK=32 4-buf counted-vmcnt -- 2x loop
//   iterations x fixed overhead > saved barrier cost. Barrier count was
//   never the limiter on this geometry.
// R15 (this round, instrumentation): gemm split into 3 per-z dispatches
//   (pre-offset pointers, zero kernel change; 256 blocks each = exactly
//   1 block/CU round, ~38us each) so attn_mix (~110us) finally TOPS the
//   PMC table -- 4 rounds of blind attn_mix edits were invariant at
//   ~55-60us/8k-tok while models said 10-25us; need its counters.
//   attn_mix byte-identical this round (unconfounded readout).
// NOTE R5: over-tight bounds force spills (FETCH explodes). Canary ~74MB.
#define TOKENS 16384
#define CHUNK  8192
#define DMODEL 1024

typedef short   short8 __attribute__((ext_vector_type(8)));
typedef _Float16 half8 __attribute__((ext_vector_type(8)));
typedef float   f32x4  __attribute__((ext_vector_type(4)));
typedef unsigned short ushort_t;
typedef unsigned short us4 __attribute__((ext_vector_type(4)));

__device__ inline ushort_t f2h(float f) {
  union { _Float16 h; ushort_t u; } x; x.h = (_Float16)f; return x.u;
}
__device__ inline float h2f(ushort_t u) {
  union { _Float16 h; ushort_t u; } x; x.u = u; return (float)x.h;
}

// ---- FP16 MFMA wrapper: dual-signature hedge (short8 vs v8f16 builtin arg) ----
template <typename V>
__device__ auto mfma16h_(V a, V b, f32x4 c, int)
    -> decltype(__builtin_amdgcn_mfma_f32_16x16x32_f16(a, b, c, 0, 0, 0)) {
  return __builtin_amdgcn_mfma_f32_16x16x32_f16(a, b, c, 0, 0, 0);
}
template <typename V>
__device__ f32x4 mfma16h_(V a, V b, f32x4 c, long) {
  return __builtin_amdgcn_mfma_f32_16x16x32_f16(
      __builtin_bit_cast(half8, a), __builtin_bit_cast(half8, b), c, 0, 0, 0);
}
__device__ inline f32x4 MFMA16H(short8 a, short8 b, f32x4 c) {
  return mfma16h_(a, b, c, 0);
}

__device__ inline void gload_lds16(const void* g, void* l) {
  __builtin_amdgcn_global_load_lds(
      (const __attribute__((address_space(1))) unsigned int*)g,
      (__attribute__((address_space(3))) unsigned int*)l, 16, 0, 0);
}

// intra-wave LDS fence (attn_mix): cross-lane ds_write -> ds_read within ONE
// wave needs only lgkmcnt(0), no s_barrier. sched_barrier stops hoisting
// past the asm (rule #18).
__device__ inline void wave_lds_fence() {
  asm volatile("s_waitcnt lgkmcnt(0)" ::: "memory");
  __builtin_amdgcn_sched_barrier(0);
}

// ---- W -> fp16, all three weights in one launch ----
__global__ __launch_bounds__(256) void conv_w(
    const float* __restrict__ Wq, const float* __restrict__ Wk,
    const float* __restrict__ Wv, ushort_t* __restrict__ Wh, int n4)
{
  int i = blockIdx.x * 256 + threadIdx.x;
  if (i >= n4) return;
  const float* src = (blockIdx.y == 0) ? Wq : ((blockIdx.y == 1) ? Wk : Wv);
  f32x4 x = ((const f32x4*)src)[i];
  us4 h;
  #pragma unroll
  for (int j = 0; j < 4; ++j) h[j] = f2h(x[j]);
  ((us4*)(Wh + (size_t)blockIdx.y * DMODEL * DMODEL))[i] = h;
}

// ---- X -> fp16 ----
__global__ __launch_bounds__(256) void conv_x(
    const float* __restrict__ src, ushort_t* __restrict__ dst, int n4)
{
  int i = blockIdx.x * 256 + threadIdx.x;
  if (i >= n4) return;
  f32x4 x = ((const f32x4*)src)[i];
  us4 h;
  #pragma unroll
  for (int j = 0; j < 4; ++j) h[j] = f2h(x[j]);
  ((us4*)dst)[i] = h;
}

// ---------------- GEMM: Y = X @ W^T, fp16, 256x256, 4-phase (R13) ----------------
// 8 waves 2Mx4N; per-wave 128x64 out = 8x4 f32x4 acc.
// LDS [2][256 rows][8 chunks of 16B]; chunk swizzle c' = c ^ (row&7), both
// sides (pre-swizzled global source + same XOR on read) -- bit-exact,
// conflict-free (R4-verified).
// K-tile schedule (4 phases, M-quadrant split):
//   ph0: ds_read B-frags(8 b128)+A-frags[0,1](4); issue stageA(t+1)
//   ph1: ds_read A-frags[2,3]; issue stageB(t+1)
//   ph2/3: ds_read A-frags[4,5]/[6,7]
//   each: s_barrier; lgkmcnt(0); setprio(1); 16 MFMA; setprio(0); s_barrier
// Tile boundary: vmcnt(0) (own next-tile loads landed; ~2500cyc lead) +
// __syncthreads (visibility of other waves' gload_lds writes).
// R15: launched per-z with pre-offset W/Y pointers (gridDim.z == 1).
__global__ __launch_bounds__(512, 2) void gemm_h(
    const ushort_t* __restrict__ Xh, const ushort_t* __restrict__ Wh,
    ushort_t* __restrict__ Y, int tokens)
{
  __shared__ ushort_t As[2][256 * 64];  // 32 KB per buffer
  __shared__ ushort_t Bs[2][256 * 64];

  const int tid  = threadIdx.x;
  const int lane = tid & 63;
  const int wid  = tid >> 6;     // 0..7
  const int quad = lane >> 4;
  const int l15  = lane & 15;
  const int wm   = wid >> 2;     // 0..1  (M split)
  const int wn   = wid & 3;      // 0..3  (N split)

  const int m0 = blockIdx.x * 256;
  const int n0 = blockIdx.y * 256;
  const int z  = blockIdx.z;     // 0 (per-z launch, pre-offset pointers)

  const ushort_t* Ag = Xh + (size_t)m0 * DMODEL;
  const ushort_t* Bg = Wh + (size_t)z * DMODEL * DMODEL + (size_t)n0 * DMODEL;
  ushort_t* Yp = Y + (size_t)z * tokens * DMODEL;

  f32x4 acc[8][4] = {};

  auto stageA = [&](int t, int b) {
    const int kbase = t * 64;
    #pragma unroll
    for (int i = 0; i < 4; ++i) {
      const int c    = i * 512 + tid;
      const int row  = c >> 3;
      const int koff = (((c & 7) ^ (row & 7)) << 3);
      gload_lds16(Ag + (size_t)row * DMODEL + kbase + koff,
                  (char*)As[b] + (i * 512 + wid * 64) * 16);
    }
  };
  auto stageB = [&](int t, int b) {
    const int kbase = t * 64;
    #pragma unroll
    for (int i = 0; i < 4; ++i) {
      const int c    = i * 512 + tid;
      const int row  = c >> 3;
      const int koff = (((c & 7) ^ (row & 7)) << 3);
      gload_lds16(Bg + (size_t)row * DMODEL + kbase + koff,
                  (char*)Bs[b] + (i * 512 + wid * 64) * 16);
    }
  };

  stageA(0, 0);
  stageB(0, 0);
  asm volatile("s_waitcnt vmcnt(0)" ::: "memory");
  __syncthreads();

  for (int t = 0; t < DMODEL / 64; ++t) {
    const int b  = t & 1;
    const bool pf = (t + 1 < DMODEL / 64);
    const short8* Av = (const short8*)As[b];  // index = row*8 + phys chunk
    const short8* Bv = (const short8*)Bs[b];

    // B-fragments for the whole tile (read in phase 0, live all 4 phases)
    short8 bh[4][2];
    #pragma unroll
    for (int j = 0; j < 4; ++j) {
      const int r = wn * 64 + j * 16 + l15;
      #pragma unroll
      for (int s = 0; s < 2; ++s)
        bh[j][s] = Bv[r * 8 + ((s * 4 + quad) ^ (r & 7))];
    }

    #pragma unroll
    for (int p = 0; p < 4; ++p) {
      short8 ah[2][2];
      #pragma unroll
      for (int ii = 0; ii < 2; ++ii) {
        const int r = wm * 128 + (2 * p + ii) * 16 + l15;
        #pragma unroll
        for (int s = 0; s < 2; ++s)
          ah[ii][s] = Av[r * 8 + ((s * 4 + quad) ^ (r & 7))];
      }
      if (p == 0 && pf) stageA(t + 1, b ^ 1);   // uniform cond, no divergence
      if (p == 1 && pf) stageB(t + 1, b ^ 1);

      __builtin_amdgcn_s_barrier();             // schedule-shaping (no drain)
      asm volatile("s_waitcnt lgkmcnt(0)" ::: "memory");
      __builtin_amdgcn_sched_barrier(0);        // rule #18
      __builtin_amdgcn_s_setprio(1);
      #pragma unroll
      for (int s = 0; s < 2; ++s) {
        #pragma unroll
        for (int ii = 0; ii < 2; ++ii) {
          #pragma unroll
          for (int j = 0; j < 4; ++j)
            acc[2 * p + ii][j] = MFMA16H(ah[ii][s], bh[j][s], acc[2 * p + ii][j]);
        }
      }
      __builtin_amdgcn_s_setprio(0);
      __builtin_amdgcn_s_barrier();
    }

    // tile boundary: own next-tile gloads landed (issued ph0/ph1, ~2500cyc
    // lead -> near-zero wait), then block-wide visibility barrier.
    if (pf) { asm volatile("s_waitcnt vmcnt(0)" ::: "memory"); }
    __syncthreads();
  }

  // C/D layout: col = lane&15, row = quad*4 + reg (verified pattern)
  #pragma unroll
  for (int i = 0; i < 8; ++i) {
    #pragma unroll
    for (int j = 0; j < 4; ++j) {
      #pragma unroll
      for (int r = 0; r < 4; ++r) {
        int row = m0 + wm * 128 + i * 16 + quad * 4 + r;
        int col = n0 + wn * 64 + j * 16 + l15;
        Yp[(size_t)row * DMODEL + col] = f2h(acc[i][j][r]);
      }
    }
  }
}

// ---------------- Phase 2: per-token mixing (1 wave/token) ----------------
// out = (smQ . sK) . V ; M = smQ.sK is 16x16, via 2 fp16 MFMAs with Q,K
// loaded straight into fragment layout (no LDS for Q/K):
//   lane l: row = l&15, k-slices quad*8 (kh0) and 32+quad*8 (kh1).
// Softmax in fragment layout, no max-subtract (N(0,1) data, fp32-safe):
//   K (over h'): per-slot lane-sums xor{1,2,4,8}; norm folded into A side.
//   Q (over d):  in-lane 16-sum + xor{16,32}.
// LDS: only V (broadcast b128 in out-phase) + M. 14.3 KB/block.
// R15: BYTE-IDENTICAL to R8/R9 -- first counter readout must be clean.
__global__ __launch_bounds__(256) void attn_mix(
    const ushort_t* __restrict__ QKV, float* __restrict__ Out, int tokens)
{
  __shared__ __align__(16) ushort_t V_s[4][16 * 72];  // stride 72 shorts
  __shared__ __align__(16) float    M_s[4][16 * 20];  // stride 20 floats

  const int tid  = threadIdx.x;
  const int lane = tid & 63;
  const int wv   = tid >> 6;
  const int tok  = blockIdx.x * 4 + wv;

  const int l15  = lane & 15;
  const int quad = lane >> 4;
  const int hrow = lane >> 3;        // V/out row pair {hrow, hrow+8}
  const int dcol = (lane & 7) * 8;   // V/out e-slice start

  ushort_t* Vl = V_s[wv];
  float*    Ml = M_s[wv];

  const size_t base = (size_t)tok * DMODEL;
  const size_t zstr = (size_t)tokens * DMODEL;
  const short8* Q8 = (const short8*)(QKV + base);
  const short8* K8 = (const short8*)(QKV + zstr + base);
  const short8* V8 = (const short8*)(QKV + 2 * zstr + base);

  // ---- V coalesced -> LDS (fp16 bits, read back broadcast in out-phase) ----
  short8 vra = V8[lane], vrb = V8[64 + lane];
  *(short8*)(Vl + hrow * 72 + dcol)       = vra;
  *(short8*)(Vl + (hrow + 8) * 72 + dcol) = vrb;

  // ---- Q,K in fragment layout: 16 full 64B lines per instruction ----
  const int fidx = l15 * 8 + quad;
  short8 qf0 = Q8[fidx], qf1 = Q8[fidx + 4];
  short8 kf0 = K8[fidx], kf1 = K8[fidx + 4];

  float eq0[8], eq1[8], ek0[8], ek1[8];
  #pragma unroll
  for (int j = 0; j < 8; ++j) {
    eq0[j] = __expf(h2f((ushort_t)qf0[j]));
    eq1[j] = __expf(h2f((ushort_t)qf1[j]));
    ek0[j] = __expf(h2f((ushort_t)kf0[j]));
    ek1[j] = __expf(h2f((ushort_t)kf1[j]));
  }

  // ---- K sums S[d] over h' (reduce over l15 within quad group) ----
  float s0[8], s1[8];
  #pragma unroll
  for (int j = 0; j < 8; ++j) { s0[j] = ek0[j]; s1[j] = ek1[j]; }
  #pragma unroll
  for (int j = 0; j < 8; ++j) {
    s0[j] += __shfl_xor(s0[j], 1);
    s0[j] += __shfl_xor(s0[j], 2);
    s0[j] += __shfl_xor(s0[j], 4);
    s0[j] += __shfl_xor(s0[j], 8);
    s1[j] += __shfl_xor(s1[j], 1);
    s1[j] += __shfl_xor(s1[j], 2);
    s1[j] += __shfl_xor(s1[j], 4);
    s1[j] += __shfl_xor(s1[j], 8);
  }

  // ---- Q sum over all 64 d: in-lane 16 + quads xor{16,32} ----
  float sq = 0.f;
  #pragma unroll
  for (int j = 0; j < 8; ++j) sq += eq0[j] + eq1[j];
  sq += __shfl_xor(sq, 16);
  sq += __shfl_xor(sq, 32);
  const float invSq = __builtin_amdgcn_rcpf(sq);

  // ---- A = eQ * invSq * invS[d] (fp16), B = eK (fp16) ----
  short8 a0v, a1v, b0v, b1v;
  #pragma unroll
  for (int j = 0; j < 8; ++j) {
    a0v[j] = (short)f2h(eq0[j] * (invSq * __builtin_amdgcn_rcpf(s0[j])));
    a1v[j] = (short)f2h(eq1[j] * (invSq * __builtin_amdgcn_rcpf(s1[j])));
    b0v[j] = (short)f2h(ek0[j]);
    b1v[j] = (short)f2h(ek1[j]);
  }

  // ---- M = A . B^T via 2 fp16 MFMAs ----
  f32x4 acc = {};
  acc = MFMA16H(a0v, b0v, acc);
  acc = MFMA16H(a1v, b1v, acc);

  // C/D: M[row=quad*4+r][col=l15]
  #pragma unroll
  for (int r = 0; r < 4; ++r) Ml[(quad * 4 + r) * 20 + l15] = acc[r];

  wave_lds_fence();

  // ---- out[h][e] = sum_h' M[h][h'] * V[h'][e], h in {hrow,hrow+8} ----
  f32x4 m0[4], m1[4];
  #pragma unroll
  for (int j = 0; j < 4; ++j) {
    m0[j] = *(const f32x4*)(Ml + hrow * 20 + j * 4);
    m1[j] = *(const f32x4*)(Ml + (hrow + 8) * 20 + j * 4);
  }
  float o0[8] = {0.f, 0.f, 0.f, 0.f, 0.f, 0.f, 0.f, 0.f};
  float o1[8] = {0.f, 0.f, 0.f, 0.f, 0.f, 0.f, 0.f, 0.f};
  #pragma unroll
  for (int hp = 0; hp < 16; ++hp) {
    short8 vv = *(const short8*)(Vl + hp * 72 + dcol);  // 8-way broadcast read
    const float w0 = m0[hp >> 2][hp & 3];
    const float w1 = m1[hp >> 2][hp & 3];
    #pragma unroll
    for (int j = 0; j < 8; ++j) {
      float vf = h2f((ushort_t)vv[j]);
      o0[j] += w0 * vf;
      o1[j] += w1 * vf;
    }
  }

  float* O0 = Out + base + hrow * 64 + dcol;
  float* O1 = Out + base + (hrow + 8) * 64 + dcol;
  f32x4 w;
  w[0] = o0[0]; w[1] = o0[1]; w[2] = o0[2]; w[3] = o0[3]; *(f32x4*)(O0)     = w;
  w[0] = o0[4]; w[1] = o0[5]; w[2] = o0[6]; w[3] = o0[7]; *(f32x4*)(O0 + 4) = w;
  w[0] = o1[0]; w[1] = o1[1]; w[2] = o1[2]; w[3] = o1[3]; *(f32x4*)(O1)     = w;
  w[0] = o1[4]; w[1] = o1[5]; w[2] = o1[6]; w[3] = o1[7]; *(f32x4*)(O1 + 4) = w;
}

extern "C" void kernel_launch(void* const* d_in, const int* in_sizes, int n_in,
                              void* d_out, int out_size, void* d_ws, size_t ws_size,
                              hipStream_t stream) {
  const float* X  = (const float*)d_in[0];
  const float* Wq = (const float*)d_in[1];
  const float* Wk = (const float*)d_in[2];
  const float* Wv = (const float*)d_in[3];
  float* Out = (float*)d_out;

  const size_t WSZ = (size_t)DMODEL * DMODEL;

  // Adaptive chunking: single pass (M=16384) if ws fits 140MB.
  const size_t need1 = (3 * WSZ + (size_t)TOKENS * DMODEL * 4) * sizeof(ushort_t);
  const int    nck  = (ws_size >= need1) ? 1 : 2;
  const size_t ctok = (nck == 1) ? (size_t)TOKENS : (size_t)CHUNK;

  ushort_t* Wh = (ushort_t*)d_ws;
  ushort_t* Xh = Wh + 3 * WSZ;
  ushort_t* Yw = Xh + ctok * DMODEL;

  const int wn4 = (int)(WSZ / 4);
  dim3 gw((wn4 + 255) / 256, 3);
  conv_w<<<gw, 256, 0, stream>>>(Wq, Wk, Wv, Wh, wn4);

  const int xn4 = (int)(ctok * DMODEL / 4);
  // R15: per-z gemm dispatches (pre-offset pointers). Each = ctok/256 x 4
  // blocks = exactly 1-block/CU rounds; makes attn_mix the longest dispatch
  // so its PMC counters finally become visible.
  dim3 gg((unsigned)(ctok / 256), DMODEL / 256, 1);
  for (int c = 0; c < nck; ++c) {
    conv_x<<<(xn4 + 255) / 256, 256, 0, stream>>>(X + c * ctok * DMODEL, Xh, xn4);
    for (int z = 0; z < 3; ++z) {
      gemm_h<<<gg, 512, 0, stream>>>(Xh, Wh + (size_t)z * WSZ,
                                     Yw + (size_t)z * ctok * DMODEL, (int)ctok);
    }
    attn_mix<<<(unsigned)(ctok / 4), 256, 0, stream>>>(Yw, Out + c * ctok * DMODEL, (int)ctok);
  }
}

// Round 11
// 261.755 us; speedup vs baseline: 1.0727x; 1.0331x over previous
//
#include <hip/hip_runtime.h>
#include <stdint.h>
#include <stddef.h>

// EfficientAttention: B=4, L=4096, D=1024, H=16, hd=64. Inputs fp32.
// R10: FP16 single-term (verified). attn_mix: out = (smQ·sK)·V, M 16x16.
// R13 (verified 114.5us, MfmaUtil 38%): 256x256, BK=64, 4-phase M-quadrant
//   interleave. R14 (BK=32 counted-vmcnt): REGRESSED 140us, reverted.
// R15 instrumentation findings (IMPORTANT):
//   - attn_mix <= 41.7us (absent from top-5 whose 5th = 41.7us gemm). The
//     "attn_mix ~110us" accounting of R2..R9 was WRONG; there is a constant
//     ~80us NON-KERNEL overhead (graph replay + reset() memsets + ~10us/launch)
//     in dur_us. attn_mix is near its ~27us BW floor. Stop optimizing it.
//   - 3-way split gemm cost 128 vs 114.5 merged -> merged launch restored.
//   - gemm structural analysis: 8 waves x 24 ds_read_b128/tile = 196KB/CU
//     @85B/cyc = 2313cyc > MFMA 2064cyc -> LDS-READ-BW-BOUND (ceiling ~47%
//     MfmaUtil; measured 38% = 80% of it). Schedule tuning can't fix BW.
// R16: B removed from LDS. conv_w emits W in FRAGMENT-MAJOR layout (1KB
//   blocks = one MFMA B-operand's 64 lane-chunks contiguous); gemm loads B
//   global->VGPR coalesced (base + lane*16), prefetched 1 tile ahead into a
//   reg double-buffer (two named arrays, unroll-by-2 -- rule #20). LDS now
//   A-only: 16 reads/wave/tile = 128KB/CU = 1542cyc < MFMA 2064 -> MFMA-bound.
//   W is 6.3MB = L2/L3-hot; B L2 traffic ~393MB/90us = 4.4TB/s << 34.5 ceiling.
//   A path + 4-phase skeleton + accumulation order unchanged -> absmax must
//   stay exactly 0.0078125. Spill canary: VGPR ~230/256, FETCH ~74MB.
#define TOKENS 16384
#define CHUNK  8192
#define DMODEL 1024

typedef short   short8 __attribute__((ext_vector_type(8)));
typedef _Float16 half8 __attribute__((ext_vector_type(8)));
typedef float   f32x4  __attribute__((ext_vector_type(4)));
typedef unsigned short ushort_t;
typedef unsigned short us4 __attribute__((ext_vector_type(4)));

__device__ inline ushort_t f2h(float f) {
  union { _Float16 h; ushort_t u; } x; x.h = (_Float16)f; return x.u;
}
__device__ inline float h2f(ushort_t u) {
  union { _Float16 h; ushort_t u; } x; x.u = u; return (float)x.h;
}

// ---- FP16 MFMA wrapper: dual-signature hedge (short8 vs v8f16 builtin arg) ----
template <typename V>
__device__ auto mfma16h_(V a, V b, f32x4 c, int)
    -> decltype(__builtin_amdgcn_mfma_f32_16x16x32_f16(a, b, c, 0, 0, 0)) {
  return __builtin_amdgcn_mfma_f32_16x16x32_f16(a, b, c, 0, 0, 0);
}
template <typename V>
__device__ f32x4 mfma16h_(V a, V b, f32x4 c, long) {
  return __builtin_amdgcn_mfma_f32_16x16x32_f16(
      __builtin_bit_cast(half8, a), __builtin_bit_cast(half8, b), c, 0, 0, 0);
}
__device__ inline f32x4 MFMA16H(short8 a, short8 b, f32x4 c) {
  return mfma16h_(a, b, c, 0);
}

__device__ inline void gload_lds16(const void* g, void* l) {
  __builtin_amdgcn_global_load_lds(
      (const __attribute__((address_space(1))) unsigned int*)g,
      (__attribute__((address_space(3))) unsigned int*)l, 16, 0, 0);
}

// intra-wave LDS fence (attn_mix): cross-lane ds_write -> ds_read within ONE
// wave needs only lgkmcnt(0), no s_barrier. sched_barrier stops hoisting
// past the asm (rule #18).
__device__ inline void wave_lds_fence() {
  asm volatile("s_waitcnt lgkmcnt(0)" ::: "memory");
  __builtin_amdgcn_sched_barrier(0);
}

// ---- W -> fp16 in FRAGMENT-MAJOR layout ----
// chunk c (per z): lane = c&63, s = (c>>6)&1, t = (c>>7)&15, G = c>>11.
// Wf[z][c][0..7] = W[G*16 + (lane&15)][t*64 + s*32 + (lane>>4)*8 + 0..7].
// gemm B-frag (G,t,s) read = global_load_dwordx4 at blockbase + lane*16 (1KB,
// perfectly coalesced). Writes here coalesced 16B; reads scattered 32B (6MB
// once, ~5us).
__global__ __launch_bounds__(256) void conv_wf(
    const float* __restrict__ Wq, const float* __restrict__ Wk,
    const float* __restrict__ Wv, ushort_t* __restrict__ Wf)
{
  const int z = blockIdx.y;
  const int c = blockIdx.x * 256 + threadIdx.x;   // 0..131071
  const float* src = (z == 0) ? Wq : ((z == 1) ? Wk : Wv);
  const int lane = c & 63;
  const int s    = (c >> 6) & 1;
  const int t    = (c >> 7) & 15;
  const int G    = c >> 11;
  const int row  = G * 16 + (lane & 15);
  const int k    = t * 64 + s * 32 + (lane >> 4) * 8;
  const float* sp = src + (size_t)row * DMODEL + k;
  f32x4 a = *(const f32x4*)sp;
  f32x4 b = *(const f32x4*)(sp + 4);
  short8 h;
  #pragma unroll
  for (int j = 0; j < 4; ++j) {
    h[j]     = (short)f2h(a[j]);
    h[4 + j] = (short)f2h(b[j]);
  }
  *(short8*)(Wf + (size_t)z * DMODEL * DMODEL + (size_t)c * 8) = h;
}

// ---- X -> fp16 ----
__global__ __launch_bounds__(256) void conv_x(
    const float* __restrict__ src, ushort_t* __restrict__ dst, int n4)
{
  int i = blockIdx.x * 256 + threadIdx.x;
  if (i >= n4) return;
  f32x4 x = ((const f32x4*)src)[i];
  us4 h;
  #pragma unroll
  for (int j = 0; j < 4; ++j) h[j] = f2h(x[j]);
  ((us4*)dst)[i] = h;
}

// ------ GEMM: Y[z] = X @ W[z]^T, fp16, 256x256, 4-phase, B-from-global ------
// 8 waves 2Mx4N; per-wave 128x64 out = 8x4 f32x4 acc.
// A in LDS [2][256 rows][8 chunks], swizzle c' = c ^ (row&7) both-sides
// (R4-verified, zero-conflict). B in VGPRs: 8 coalesced dwordx4 per wave per
// tile from fragment-major Wf (L2-hot), reg-dbuf'd one tile ahead.
// K-tile schedule (4 phases, M-quadrant split):
//   ph0: ds_read A[0,1]; issue stageA(t+1) + ldB_lo(t+1)
//   ph1: ds_read A[2,3]; issue ldB_hi(t+1);  ph2/3: A[4,5]/[6,7]
//   each: s_barrier; lgkmcnt(0); setprio(1); 16 MFMA; setprio(0); s_barrier
// Tile boundary: vmcnt(0) (covers own A-stage AND B-prefetch, ~2500cyc lead)
// + __syncthreads (visibility of other waves' gload_lds writes).
__global__ __launch_bounds__(512, 2) void gemm_h(
    const ushort_t* __restrict__ Xh, const ushort_t* __restrict__ Wf,
    ushort_t* __restrict__ Y, int tokens)
{
  __shared__ ushort_t As[2][256 * 64];  // 32 KB per buffer, 64 KB total

  const int tid  = threadIdx.x;
  const int lane = tid & 63;
  const int wid  = tid >> 6;     // 0..7
  const int quad = lane >> 4;
  const int l15  = lane & 15;
  const int wm   = wid >> 2;     // 0..1  (M split)
  const int wn   = wid & 3;      // 0..3  (N split)

  const int m0   = blockIdx.x * 256;
  const int by16 = blockIdx.y * 16;   // col-group base (16 G per block)
  const int z    = blockIdx.z;

  const ushort_t* Ag = Xh + (size_t)m0 * DMODEL;
  const ushort_t* Bf = Wf + (size_t)z * DMODEL * DMODEL;
  ushort_t* Yp = Y + (size_t)z * tokens * DMODEL;

  f32x4 acc[8][4] = {};

  auto stageA = [&](int t, int b) {
    const int kbase = t * 64;
    #pragma unroll
    for (int i = 0; i < 4; ++i) {
      const int c    = i * 512 + tid;
      const int row  = c >> 3;
      const int koff = (((c & 7) ^ (row & 7)) << 3);
      gload_lds16(Ag + (size_t)row * DMODEL + kbase + koff,
                  (char*)As[b] + (i * 512 + wid * 64) * 16);
    }
  };
  // B-frag (j,s) for tile t: 1KB block, lane-chunk = +lane*8 ushorts.
  auto ldB_lo = [&](int t, short8 (&dst)[4][2]) {
    #pragma unroll
    for (int j = 0; j < 2; ++j)
      #pragma unroll
      for (int s = 0; s < 2; ++s)
        dst[j][s] = *(const short8*)(
            Bf + ((((size_t)(by16 + wn * 4 + j) * 16 + t) * 2 + s) << 9) + lane * 8);
  };
  auto ldB_hi = [&](int t, short8 (&dst)[4][2]) {
    #pragma unroll
    for (int j = 2; j < 4; ++j)
      #pragma unroll
      for (int s = 0; s < 2; ++s)
        dst[j][s] = *(const short8*)(
            Bf + ((((size_t)(by16 + wn * 4 + j) * 16 + t) * 2 + s) << 9) + lane * 8);
  };

  auto body = [&](int t, short8 (&cur)[4][2], short8 (&nxt)[4][2]) {
    const int b   = t & 1;
    const bool pf = (t + 1 < DMODEL / 64);
    const short8* Av = (const short8*)As[b];  // index = row*8 + phys chunk

    #pragma unroll
    for (int p = 0; p < 4; ++p) {
      short8 ah[2][2];
      #pragma unroll
      for (int ii = 0; ii < 2; ++ii) {
        const int r = wm * 128 + (2 * p + ii) * 16 + l15;
        #pragma unroll
        for (int s = 0; s < 2; ++s)
          ah[ii][s] = Av[r * 8 + ((s * 4 + quad) ^ (r & 7))];
      }
      if (p == 0 && pf) { stageA(t + 1, b ^ 1); ldB_lo(t + 1, nxt); }
      if (p == 1 && pf) { ldB_hi(t + 1, nxt); }

      __builtin_amdgcn_s_barrier();             // schedule-shaping (no drain)
      asm volatile("s_waitcnt lgkmcnt(0)" ::: "memory");
      __builtin_amdgcn_sched_barrier(0);        // rule #18
      __builtin_amdgcn_s_setprio(1);
      #pragma unroll
      for (int s = 0; s < 2; ++s) {
        #pragma unroll
        for (int ii = 0; ii < 2; ++ii) {
          #pragma unroll
          for (int j = 0; j < 4; ++j)
            acc[2 * p + ii][j] = MFMA16H(ah[ii][s], cur[j][s], acc[2 * p + ii][j]);
        }
      }
      __builtin_amdgcn_s_setprio(0);
      __builtin_amdgcn_s_barrier();
    }

    // boundary: own A-stage AND B-prefetch landed (issued ph0/ph1, ~2500cyc
    // lead -> near-zero wait), then block-wide visibility barrier.
    if (pf) { asm volatile("s_waitcnt vmcnt(0)" ::: "memory"); }
    __syncthreads();
  };

  short8 bA[4][2], bB[4][2];   // reg double-buffer (static-indexed, rule #20)
  stageA(0, 0);
  ldB_lo(0, bA);
  ldB_hi(0, bA);
  asm volatile("s_waitcnt vmcnt(0)" ::: "memory");
  __syncthreads();

  for (int tt = 0; tt < DMODEL / 64; tt += 2) {
    body(tt, bA, bB);
    body(tt + 1, bB, bA);
  }

  // C/D layout: col = lane&15, row = quad*4 + reg (verified pattern)
  #pragma unroll
  for (int i = 0; i < 8; ++i) {
    #pragma unroll
    for (int j = 0; j < 4; ++j) {
      #pragma unroll
      for (int r = 0; r < 4; ++r) {
        int row = m0 + wm * 128 + i * 16 + quad * 4 + r;
        int col = blockIdx.y * 256 + wn * 64 + j * 16 + l15;
        Yp[(size_t)row * DMODEL + col] = f2h(acc[i][j][r]);
      }
    }
  }
}

// ---------------- Phase 2: per-token mixing (1 wave/token) ----------------
// out = (smQ . sK) . V ; M = smQ.sK is 16x16, via 2 fp16 MFMAs with Q,K
// loaded straight into fragment layout (no LDS for Q/K).
// R15 finding: this kernel is <= 42us (near its ~27us BW floor). UNCHANGED.
__global__ __launch_bounds__(256) void attn_mix(
    const ushort_t* __restrict__ QKV, float* __restrict__ Out, int tokens)
{
  __shared__ __align__(16) ushort_t V_s[4][16 * 72];  // stride 72 shorts
  __shared__ __align__(16) float    M_s[4][16 * 20];  // stride 20 floats

  const int tid  = threadIdx.x;
  const int lane = tid & 63;
  const int wv   = tid >> 6;
  const int tok  = blockIdx.x * 4 + wv;

  const int l15  = lane & 15;
  const int quad = lane >> 4;
  const int hrow = lane >> 3;        // V/out row pair {hrow, hrow+8}
  const int dcol = (lane & 7) * 8;   // V/out e-slice start

  ushort_t* Vl = V_s[wv];
  float*    Ml = M_s[wv];

  const size_t base = (size_t)tok * DMODEL;
  const size_t zstr = (size_t)tokens * DMODEL;
  const short8* Q8 = (const short8*)(QKV + base);
  const short8* K8 = (const short8*)(QKV + zstr + base);
  const short8* V8 = (const short8*)(QKV + 2 * zstr + base);

  // ---- V coalesced -> LDS (fp16 bits, read back broadcast in out-phase) ----
  short8 vra = V8[lane], vrb = V8[64 + lane];
  *(short8*)(Vl + hrow * 72 + dcol)       = vra;
  *(short8*)(Vl + (hrow + 8) * 72 + dcol) = vrb;

  // ---- Q,K in fragment layout: 16 full 64B lines per instruction ----
  const int fidx = l15 * 8 + quad;
  short8 qf0 = Q8[fidx], qf1 = Q8[fidx + 4];
  short8 kf0 = K8[fidx], kf1 = K8[fidx + 4];

  float eq0[8], eq1[8], ek0[8], ek1[8];
  #pragma unroll
  for (int j = 0; j < 8; ++j) {
    eq0[j] = __expf(h2f((ushort_t)qf0[j]));
    eq1[j] = __expf(h2f((ushort_t)qf1[j]));
    ek0[j] = __expf(h2f((ushort_t)kf0[j]));
    ek1[j] = __expf(h2f((ushort_t)kf1[j]));
  }

  // ---- K sums S[d] over h' (reduce over l15 within quad group) ----
  float s0[8], s1[8];
  #pragma unroll
  for (int j = 0; j < 8; ++j) { s0[j] = ek0[j]; s1[j] = ek1[j]; }
  #pragma unroll
  for (int j = 0; j < 8; ++j) {
    s0[j] += __shfl_xor(s0[j], 1);
    s0[j] += __shfl_xor(s0[j], 2);
    s0[j] += __shfl_xor(s0[j], 4);
    s0[j] += __shfl_xor(s0[j], 8);
    s1[j] += __shfl_xor(s1[j], 1);
    s1[j] += __shfl_xor(s1[j], 2);
    s1[j] += __shfl_xor(s1[j], 4);
    s1[j] += __shfl_xor(s1[j], 8);
  }

  // ---- Q sum over all 64 d: in-lane 16 + quads xor{16,32} ----
  float sq = 0.f;
  #pragma unroll
  for (int j = 0; j < 8; ++j) sq += eq0[j] + eq1[j];
  sq += __shfl_xor(sq, 16);
  sq += __shfl_xor(sq, 32);
  const float invSq = __builtin_amdgcn_rcpf(sq);

  // ---- A = eQ * invSq * invS[d] (fp16), B = eK (fp16) ----
  short8 a0v, a1v, b0v, b1v;
  #pragma unroll
  for (int j = 0; j < 8; ++j) {
    a0v[j] = (short)f2h(eq0[j] * (invSq * __builtin_amdgcn_rcpf(s0[j])));
    a1v[j] = (short)f2h(eq1[j] * (invSq * __builtin_amdgcn_rcpf(s1[j])));
    b0v[j] = (short)f2h(ek0[j]);
    b1v[j] = (short)f2h(ek1[j]);
  }

  // ---- M = A . B^T via 2 fp16 MFMAs ----
  f32x4 acc = {};
  acc = MFMA16H(a0v, b0v, acc);
  acc = MFMA16H(a1v, b1v, acc);

  // C/D: M[row=quad*4+r][col=l15]
  #pragma unroll
  for (int r = 0; r < 4; ++r) Ml[(quad * 4 + r) * 20 + l15] = acc[r];

  wave_lds_fence();

  // ---- out[h][e] = sum_h' M[h][h'] * V[h'][e], h in {hrow,hrow+8} ----
  f32x4 m0[4], m1[4];
  #pragma unroll
  for (int j = 0; j < 4; ++j) {
    m0[j] = *(const f32x4*)(Ml + hrow * 20 + j * 4);
    m1[j] = *(const f32x4*)(Ml + (hrow + 8) * 20 + j * 4);
  }
  float o0[8] = {0.f, 0.f, 0.f, 0.f, 0.f, 0.f, 0.f, 0.f};
  float o1[8] = {0.f, 0.f, 0.f, 0.f, 0.f, 0.f, 0.f, 0.f};
  #pragma unroll
  for (int hp = 0; hp < 16; ++hp) {
    short8 vv = *(const short8*)(Vl + hp * 72 + dcol);  // 8-way broadcast read
    const float w0 = m0[hp >> 2][hp & 3];
    const float w1 = m1[hp >> 2][hp & 3];
    #pragma unroll
    for (int j = 0; j < 8; ++j) {
      float vf = h2f((ushort_t)vv[j]);
      o0[j] += w0 * vf;
      o1[j] += w1 * vf;
    }
  }

  float* O0 = Out + base + hrow * 64 + dcol;
  float* O1 = Out + base + (hrow + 8) * 64 + dcol;
  f32x4 w;
  w[0] = o0[0]; w[1] = o0[1]; w[2] = o0[2]; w[3] = o0[3]; *(f32x4*)(O0)     = w;
  w[0] = o0[4]; w[1] = o0[5]; w[2] = o0[6]; w[3] = o0[7]; *(f32x4*)(O0 + 4) = w;
  w[0] = o1[0]; w[1] = o1[1]; w[2] = o1[2]; w[3] = o1[3]; *(f32x4*)(O1)     = w;
  w[0] = o1[4]; w[1] = o1[5]; w[2] = o1[6]; w[3] = o1[7]; *(f32x4*)(O1 + 4) = w;
}

extern "C" void kernel_launch(void* const* d_in, const int* in_sizes, int n_in,
                              void* d_out, int out_size, void* d_ws, size_t ws_size,
                              hipStream_t stream) {
  const float* X  = (const float*)d_in[0];
  const float* Wq = (const float*)d_in[1];
  const float* Wk = (const float*)d_in[2];
  const float* Wv = (const float*)d_in[3];
  float* Out = (float*)d_out;

  const size_t WSZ = (size_t)DMODEL * DMODEL;

  // Adaptive chunking: single pass (M=16384) if ws fits 140MB.
  const size_t need1 = (3 * WSZ + (size_t)TOKENS * DMODEL * 4) * sizeof(ushort_t);
  const int    nck  = (ws_size >= need1) ? 1 : 2;
  const size_t ctok = (nck == 1) ? (size_t)TOKENS : (size_t)CHUNK;

  ushort_t* Wf = (ushort_t*)d_ws;
  ushort_t* Xh = Wf + 3 * WSZ;
  ushort_t* Yw = Xh + ctok * DMODEL;

  // fragment-major W (128K chunks of 8 elems per z)
  dim3 gw(512, 3);
  conv_wf<<<gw, 256, 0, stream>>>(Wq, Wk, Wv, Wf);

  const int xn4 = (int)(ctok * DMODEL / 4);
  dim3 gg((unsigned)(ctok / 256), DMODEL / 256, 3);   // merged (R15: split cost +14us)
  for (int c = 0; c < nck; ++c) {
    conv_x<<<(xn4 + 255) / 256, 256, 0, stream>>>(X + c * ctok * DMODEL, Xh, xn4);
    gemm_h<<<gg, 512, 0, stream>>>(Xh, Wf, Yw, (int)ctok);
    attn_mix<<<(unsigned)(ctok / 4), 256, 0, stream>>>(Yw, Out + c * ctok * DMODEL, (int)ctok);
  }
}